// Round 9
// baseline (81.954 us; speedup 1.0000x reference)
//
#include <hip/hip_runtime.h>

// CrossNetLayer, 2 dispatches.
//   prep: W fp32[k][n] -> Wt f16[n][k]; x fp32 -> xh f16;
//         cvec[4], evec[4], beta4[1024]; g_l = W_enc @ w_l (f16 [4][1024]).
//   gemm+cross: h = xh @ Wt^T; d computed via extra MFMA with g fragments
//         loaded DIRECTLY from global (8KB, L2-resident) into registers;
//         sig recurrence in LDS; out = sig*(h+b_enc) + beta4.
// R11: removed the Gs LDS double-buffer (8KB payload didn't justify a
// staged pipeline): g fragments hoisted per-iter as 4x half8 global loads
// on the two d-waves only. Everything else verbatim R10 (passed, 81.1us).

#define B_SZ 1024
#define D_SZ 1024
#define H_SZ 1024
#define DEPTH 4

typedef _Float16 half4_t __attribute__((ext_vector_type(4)));
typedef _Float16 half8_t __attribute__((ext_vector_type(8)));
typedef float floatx4_t __attribute__((ext_vector_type(4)));

typedef const __attribute__((address_space(1))) unsigned int* gas_ptr;
typedef __attribute__((address_space(3))) unsigned int* las_ptr;

__device__ __forceinline__ void async_copy16(const void* g, void* l) {
    // 16 B per lane; HW dest = wave-uniform base + lane*16
    __builtin_amdgcn_global_load_lds((gas_ptr)g, (las_ptr)l, 16, 0, 0);
}

// ---------------------------------------------------------------------------
// Kernel 1: prep (verbatim R10).
//   blocks 0..255  : transpose-convert W -> Wt (f16 [n][k])
//   blocks 256..511: convert x -> xh (f16)
//   block  512     : cvec[4], evec[4], beta4[1024]
//   blocks 513..576: gh[l][k] = (f16) W[k][:] . w_l  (coalesced, W once)
// ---------------------------------------------------------------------------
__global__ __launch_bounds__(256) void prep_kernel(
        const float* __restrict__ x, const float* __restrict__ W,
        const float* __restrict__ b_enc, const float* __restrict__ ws,
        const float* __restrict__ bs,
        _Float16* __restrict__ xh, _Float16* __restrict__ Wt,
        float* __restrict__ cvec, float* __restrict__ evec,
        float* __restrict__ beta4, _Float16* __restrict__ gh) {
    const int b = blockIdx.x;
    const int t = threadIdx.x;
    if (b < 256) {
        __shared__ float S[64][65];    // +1 pad: transposed reads conflict-free
        const int k0 = (b >> 4) << 6;
        const int n0 = (b & 15) << 6;
#pragma unroll
        for (int i = 0; i < 4; ++i) {
            int idx = (i << 8) + t;
            int r = idx >> 4;              // k-local 0..63
            int c4 = idx & 15;             // float4 group along n
            float4 v = *(const float4*)(W + (size_t)(k0 + r) * H_SZ + n0 + (c4 << 2));
            S[r][(c4 << 2) + 0] = v.x;
            S[r][(c4 << 2) + 1] = v.y;
            S[r][(c4 << 2) + 2] = v.z;
            S[r][(c4 << 2) + 3] = v.w;
        }
        __syncthreads();
#pragma unroll
        for (int i = 0; i < 4; ++i) {
            int idx = (i << 8) + t;
            int n = idx >> 4;              // n-local 0..63
            int c4 = idx & 15;
            int k = c4 << 2;
            half4_t o;
            o.x = (_Float16)S[k + 0][n];
            o.y = (_Float16)S[k + 1][n];
            o.z = (_Float16)S[k + 2][n];
            o.w = (_Float16)S[k + 3][n];
            *(half4_t*)(Wt + (size_t)(n0 + n) * D_SZ + k0 + k) = o;
        }
    } else if (b < 512) {
        const int base = (b - 256) * 4096;
#pragma unroll
        for (int i = 0; i < 4; ++i) {
            int off = base + (((i << 8) + t) << 2);
            float4 v = *(const float4*)(x + off);
            half4_t o;
            o.x = (_Float16)v.x; o.y = (_Float16)v.y;
            o.z = (_Float16)v.z; o.w = (_Float16)v.w;
            *(half4_t*)(xh + off) = o;
        }
    } else if (b == 512) {
        // beta_l = sum_{j<l} b_j; c_l = beta_l . w_l; e_l = b_enc . w_l
        __shared__ float redc[4][7];
        const int j = t << 2;
        float4 b0 = *(const float4*)(bs + 0 * H_SZ + j);
        float4 b1 = *(const float4*)(bs + 1 * H_SZ + j);
        float4 b2 = *(const float4*)(bs + 2 * H_SZ + j);
        float4 b3 = *(const float4*)(bs + 3 * H_SZ + j);
        float4 w0 = *(const float4*)(ws + 0 * H_SZ + j);
        float4 w1 = *(const float4*)(ws + 1 * H_SZ + j);
        float4 w2 = *(const float4*)(ws + 2 * H_SZ + j);
        float4 w3 = *(const float4*)(ws + 3 * H_SZ + j);
        float4 be = *(const float4*)(b_enc + j);
        float4 pre1 = b0;
        float4 pre2 = {pre1.x + b1.x, pre1.y + b1.y, pre1.z + b1.z, pre1.w + b1.w};
        float4 pre3 = {pre2.x + b2.x, pre2.y + b2.y, pre2.z + b2.z, pre2.w + b2.w};
        float4 bt   = {pre3.x + b3.x, pre3.y + b3.y, pre3.z + b3.z, pre3.w + b3.w};
        *(float4*)(beta4 + j) = bt;
        float pp[7];
        pp[0] = pre1.x * w1.x + pre1.y * w1.y + pre1.z * w1.z + pre1.w * w1.w;
        pp[1] = pre2.x * w2.x + pre2.y * w2.y + pre2.z * w2.z + pre2.w * w2.w;
        pp[2] = pre3.x * w3.x + pre3.y * w3.y + pre3.z * w3.z + pre3.w * w3.w;
        pp[3] = be.x * w0.x + be.y * w0.y + be.z * w0.z + be.w * w0.w;
        pp[4] = be.x * w1.x + be.y * w1.y + be.z * w1.z + be.w * w1.w;
        pp[5] = be.x * w2.x + be.y * w2.y + be.z * w2.z + be.w * w2.w;
        pp[6] = be.x * w3.x + be.y * w3.y + be.z * w3.z + be.w * w3.w;
#pragma unroll
        for (int off = 32; off > 0; off >>= 1) {
#pragma unroll
            for (int l = 0; l < 7; ++l) pp[l] += __shfl_down(pp[l], off, 64);
        }
        if ((t & 63) == 0) {
#pragma unroll
            for (int l = 0; l < 7; ++l) redc[t >> 6][l] = pp[l];
        }
        __syncthreads();
        if (t == 0) {
            cvec[0] = 0.0f;
#pragma unroll
            for (int l = 0; l < 3; ++l)
                cvec[l + 1] = redc[0][l] + redc[1][l] + redc[2][l] + redc[3][l];
#pragma unroll
            for (int l = 0; l < 4; ++l)
                evec[l] = redc[0][3 + l] + redc[1][3 + l] +
                          redc[2][3 + l] + redc[3][3 + l];
        }
    } else {
        // g vectors, coalesced: block owns rows k0..k0+15; W read ONCE;
        // all 4 layers dotted simultaneously. Wave reads a whole row
        // (lane l covers cols l*4 + i*256, i=0..3 -> contiguous 1KB/wave).
        const int gb = b - 513;              // 0..63
        const int k0 = gb << 4;
        const int wv4 = t >> 6;              // wave 0..3
        const int l   = t & 63;
        float4 wsv0[4], wsv1[4], wsv2[4], wsv3[4];   // [i] per layer
#pragma unroll
        for (int i = 0; i < 4; ++i) {
            wsv0[i] = *(const float4*)(ws + 0 * H_SZ + (i << 8) + (l << 2));
            wsv1[i] = *(const float4*)(ws + 1 * H_SZ + (i << 8) + (l << 2));
            wsv2[i] = *(const float4*)(ws + 2 * H_SZ + (i << 8) + (l << 2));
            wsv3[i] = *(const float4*)(ws + 3 * H_SZ + (i << 8) + (l << 2));
        }
#pragma unroll
        for (int p = 0; p < 4; ++p) {
            const int row = k0 + (p << 2) + wv4;
            const float* wr = W + (size_t)row * H_SZ;
            float4 wrow[4];
#pragma unroll
            for (int i = 0; i < 4; ++i)
                wrow[i] = *(const float4*)(wr + (i << 8) + (l << 2));
            float d0 = 0.f, d1 = 0.f, d2 = 0.f, d3 = 0.f;
#pragma unroll
            for (int i = 0; i < 4; ++i) {
                d0 += wrow[i].x * wsv0[i].x + wrow[i].y * wsv0[i].y +
                      wrow[i].z * wsv0[i].z + wrow[i].w * wsv0[i].w;
                d1 += wrow[i].x * wsv1[i].x + wrow[i].y * wsv1[i].y +
                      wrow[i].z * wsv1[i].z + wrow[i].w * wsv1[i].w;
                d2 += wrow[i].x * wsv2[i].x + wrow[i].y * wsv2[i].y +
                      wrow[i].z * wsv2[i].z + wrow[i].w * wsv2[i].w;
                d3 += wrow[i].x * wsv3[i].x + wrow[i].y * wsv3[i].y +
                      wrow[i].z * wsv3[i].z + wrow[i].w * wsv3[i].w;
            }
#pragma unroll
            for (int off = 32; off > 0; off >>= 1) {
                d0 += __shfl_xor(d0, off, 64);
                d1 += __shfl_xor(d1, off, 64);
                d2 += __shfl_xor(d2, off, 64);
                d3 += __shfl_xor(d3, off, 64);
            }
            if (l == 0) {        // static stores only (no runtime reg-index)
                gh[0 * D_SZ + row] = (_Float16)d0;
                gh[1 * D_SZ + row] = (_Float16)d1;
                gh[2 * D_SZ + row] = (_Float16)d2;
                gh[3 * D_SZ + row] = (_Float16)d3;
            }
        }
    }
}

// ---------------------------------------------------------------------------
// Kernel 2: GEMM + MFMA-fused crossnet. BM=32, BN=64, BK=128. 512 thr =
// 8 waves in 2(m) x 4(n). grid (16,32) = 512 blocks = 2/CU.
// Waves 0,4 also compute d = xh_rows @ g^T via one extra MFMA per kk;
// g fragments loaded per-iter straight from global (L2-hot 8KB) into regs.
// Epilogue: sig recurrence via LDS, out = sig*(acc+b_enc) + beta4.
// ---------------------------------------------------------------------------
__global__ __launch_bounds__(512, 2) void gemm_cross_kernel(
        const _Float16* __restrict__ xh, const _Float16* __restrict__ Wt,
        const float* __restrict__ b_enc, const _Float16* __restrict__ gh,
        const float* __restrict__ cvec, const float* __restrict__ evec,
        const float* __restrict__ beta4, float* __restrict__ h) {
    __shared__ _Float16 As[2][32 * 128];   //  8 KB / buf
    __shared__ _Float16 Bs[2][64 * 128];   // 16 KB / buf
    __shared__ float dS[32][4];
    __shared__ float sigS[32];
    const int tid  = threadIdx.x;
    const int lane = tid & 63;
    const int w    = tid >> 6;            // 0..7
    const int m0 = blockIdx.y << 5;
    const int n0 = blockIdx.x << 6;
    const int wm = (w >> 2) << 4;         // 0 / 16
    const int wn = (w & 3) << 4;          // 0 / 16 / 32 / 48

    // staging: A 512 slots (1/thread), B 1024 slots (2/thread).
    // slot s -> row r = s>>4, phys chunk s&15, logical chunk (s&15)^(r&15).
    const int ar = tid >> 4;                       // 0..31
    const int ac = ((tid & 15) ^ (ar & 15)) << 3;
    const int br0 = tid >> 4;                      // 0..31
    const int bc0 = ((tid & 15) ^ (br0 & 15)) << 3;
    const int br1 = br0 + 32;                      // 32..63
    const int bc1 = ((tid & 15) ^ (br1 & 15)) << 3;
    const _Float16* aSrc  = xh + (size_t)(m0 + ar) * D_SZ + ac;
    const _Float16* bSrc0 = Wt + (size_t)(n0 + br0) * D_SZ + bc0;
    const _Float16* bSrc1 = Wt + (size_t)(n0 + br1) * D_SZ + bc1;

    // fragment geometry (16x16x32): A[m=lane&15][k=q*8+j], B symmetric.
    const int ra = wm + (lane & 15);
    const int rb = wn + (lane & 15);
    const int q  = lane >> 4;
    const bool dwave = (w & 3) == 0;      // waves 0,4 run the d-path
    // g fragment base: row (lane&15) of gh (rows 4..15 read in-ws garbage;
    // their D-columns are discarded - no cross-column mixing in MFMA).
    const _Float16* gBase = gh + (size_t)(lane & 15) * D_SZ + (q << 3);

    floatx4_t acc  = {0.0f, 0.0f, 0.0f, 0.0f};
    floatx4_t dacc = {0.0f, 0.0f, 0.0f, 0.0f};

    async_copy16(aSrc, &As[0][tid << 3]);
    async_copy16(bSrc0, &Bs[0][tid << 3]);
    async_copy16(bSrc1, &Bs[0][(tid + 512) << 3]);

    for (int it = 0; it < 8; ++it) {
        __syncthreads();   // drains stage(it); all waves done reading buf[(it+1)&1]
        if (it + 1 < 8) {
            int k0 = (it + 1) << 7;
            int buf = (it + 1) & 1;
            async_copy16(aSrc + k0, &As[buf][tid << 3]);
            async_copy16(bSrc0 + k0, &Bs[buf][tid << 3]);
            async_copy16(bSrc1 + k0, &Bs[buf][(tid + 512) << 3]);
        }
        const _Float16* Ab = As[it & 1];
        const _Float16* Bb = Bs[it & 1];
        // hoist this iter's 4 g fragments (L2-hit; hidden under kk bodies)
        half8_t g0, g1, g2, g3;
        if (dwave) {
            const _Float16* gp = gBase + (it << 7);
            g0 = *(const half8_t*)(gp);
            g1 = *(const half8_t*)(gp + 32);
            g2 = *(const half8_t*)(gp + 64);
            g3 = *(const half8_t*)(gp + 96);
        }
#pragma unroll
        for (int kk = 0; kk < 4; ++kk) {
            int l = (kk << 2) + q;
            half8_t af = *(const half8_t*)(Ab + ra * 128 + ((l ^ (ra & 15)) << 3));
            half8_t bf = *(const half8_t*)(Bb + rb * 128 + ((l ^ (rb & 15)) << 3));
            acc = __builtin_amdgcn_mfma_f32_16x16x32_f16(af, bf, acc, 0, 0, 0);
            if (dwave) {   // static kk -> folds to a direct register use
                half8_t gf = (kk == 0) ? g0 : (kk == 1) ? g1 : (kk == 2) ? g2 : g3;
                dacc = __builtin_amdgcn_mfma_f32_16x16x32_f16(af, gf, dacc, 0, 0, 0);
            }
        }
    }

    // ---- d -> sig (cols 0..3 of dacc = layers; cols 4..15 garbage) ----
    if (dwave && (lane & 15) < 4) {
#pragma unroll
        for (int r = 0; r < 4; ++r)
            dS[wm + (q << 2) + r][lane & 15] = dacc[r];
    }
    __syncthreads();
    if (tid < 32) {
        const float4 cv = *(const float4*)cvec;
        const float4 ev = *(const float4*)evec;
        float d0 = dS[tid][0] + ev.x;
        float d1 = dS[tid][1] + ev.y;
        float d2 = dS[tid][2] + ev.z;
        float d3 = dS[tid][3] + ev.w;
        float sig = 1.0f, s;
        s = sig * d0 + cv.x; sig += s;
        s = sig * d1 + cv.y; sig += s;
        s = sig * d2 + cv.z; sig += s;
        s = sig * d3 + cv.w; sig += s;
        sigS[tid] = sig;
    }
    __syncthreads();

    // C/D: col = lane&15, row = (lane>>4)*4 + reg.
    // out = sig * (acc + b_enc) + beta4
    const int col  = n0 + wn + (lane & 15);
    const int row0 = m0 + wm + (q << 2);
    const float be  = b_enc[col];
    const float bt4 = beta4[col];
#pragma unroll
    for (int r = 0; r < 4; ++r) {
        float sig = sigS[wm + (q << 2) + r];
        h[(size_t)(row0 + r) * H_SZ + col] = sig * (acc[r] + be) + bt4;
    }
}

extern "C" void kernel_launch(void* const* d_in, const int* in_sizes, int n_in,
                              void* d_out, int out_size, void* d_ws, size_t ws_size,
                              hipStream_t stream) {
    const float* x     = (const float*)d_in[0];
    const float* W_enc = (const float*)d_in[1];
    const float* b_enc = (const float*)d_in[2];
    const float* ws    = (const float*)d_in[3];
    const float* bs    = (const float*)d_in[4];
    float* out = (float*)d_out;

    _Float16* xh = (_Float16*)d_ws;                 // 2 MB
    _Float16* Wt = xh + (size_t)B_SZ * D_SZ;        // 2 MB
    float* aux   = (float*)((char*)d_ws + 4u * 1024u * 1024u);
    float* cvec  = aux;                             // 4 floats
    float* evec  = aux + 4;                         // 4 floats
    float* beta4 = aux + 8;                         // 1024 floats
    _Float16* gh = (_Float16*)(aux + 8 + H_SZ);     // 4x1024 f16 (8 KB)

    prep_kernel<<<577, 256, 0, stream>>>(x, W_enc, b_enc, ws, bs,
                                         xh, Wt, cvec, evec, beta4, gh);
    dim3 grid(H_SZ / 64, B_SZ / 32);                // (n-tiles, m-tiles)
    gemm_cross_kernel<<<grid, 512, 0, stream>>>(xh, Wt, b_enc, gh,
                                                cvec, evec, beta4, out);
}

// Round 10
// 79.919 us; speedup vs baseline: 1.0255x; 1.0255x over previous
//
#include <hip/hip_runtime.h>

// CrossNetLayer, 3 dispatches. FINAL (revert to best-measured R7, 80.0us).
//   prep:     W fp32[k][n] -> Wt f16[n][k]; x fp32 -> xh f16;
//             crossnet constants c[4], beta4[1024] (affine collapse).
//   gemm:     h = xh @ Wt^T + b_enc. BM=32 BN=64 BK=128, 8 waves,
//             grid 512 = 2 blocks/CU, dbuf XOR-swizzled LDS.
//   crossnet: out = sigma*x0 + beta4 (single-pass affine-collapsed).
// Session ledger: 82.3 (R1) -> 80.0 (R7, this) across 5 structures;
// ~42us in-window ws-poison fill + ~28us harness-fixed overhead dominate;
// kernels ~10us vs ~7us arithmetic floor. Dispatch-fusion tested twice
// (R8 fences: +70us; R10/R11 g-fusion: +1-2us) - does not pay.

#define B_SZ 1024
#define D_SZ 1024
#define H_SZ 1024
#define DEPTH 4

typedef _Float16 half4_t __attribute__((ext_vector_type(4)));
typedef _Float16 half8_t __attribute__((ext_vector_type(8)));
typedef float floatx4_t __attribute__((ext_vector_type(4)));

typedef const __attribute__((address_space(1))) unsigned int* gas_ptr;
typedef __attribute__((address_space(3))) unsigned int* las_ptr;

__device__ __forceinline__ void async_copy16(const void* g, void* l) {
    // 16 B per lane; HW dest = wave-uniform base + lane*16
    __builtin_amdgcn_global_load_lds((gas_ptr)g, (las_ptr)l, 16, 0, 0);
}

// ---------------------------------------------------------------------------
// Kernel 1: prep. Blocks 0..255: transpose-convert W; 256..511: convert x;
// block 512: crossnet constants c_l = (sum_{j<l} b_j) . w_l and beta4.
// ---------------------------------------------------------------------------
__global__ __launch_bounds__(256) void prep_kernel(
        const float* __restrict__ x, const float* __restrict__ W,
        const float* __restrict__ ws, const float* __restrict__ bs,
        _Float16* __restrict__ xh, _Float16* __restrict__ Wt,
        float* __restrict__ cvec, float* __restrict__ beta4) {
    const int b = blockIdx.x;
    const int t = threadIdx.x;
    if (b < 256) {
        __shared__ float S[64][65];    // +1 pad: transposed reads conflict-free
        const int k0 = (b >> 4) << 6;
        const int n0 = (b & 15) << 6;
#pragma unroll
        for (int i = 0; i < 4; ++i) {
            int idx = (i << 8) + t;
            int r = idx >> 4;              // k-local 0..63
            int c4 = idx & 15;             // float4 group along n
            float4 v = *(const float4*)(W + (size_t)(k0 + r) * H_SZ + n0 + (c4 << 2));
            S[r][(c4 << 2) + 0] = v.x;
            S[r][(c4 << 2) + 1] = v.y;
            S[r][(c4 << 2) + 2] = v.z;
            S[r][(c4 << 2) + 3] = v.w;
        }
        __syncthreads();
#pragma unroll
        for (int i = 0; i < 4; ++i) {
            int idx = (i << 8) + t;
            int n = idx >> 4;              // n-local 0..63
            int c4 = idx & 15;
            int k = c4 << 2;
            half4_t o;
            o.x = (_Float16)S[k + 0][n];
            o.y = (_Float16)S[k + 1][n];
            o.z = (_Float16)S[k + 2][n];
            o.w = (_Float16)S[k + 3][n];
            *(half4_t*)(Wt + (size_t)(n0 + n) * D_SZ + k0 + k) = o;
        }
    } else if (b < 512) {
        const int base = (b - 256) * 4096;
#pragma unroll
        for (int i = 0; i < 4; ++i) {
            int off = base + (((i << 8) + t) << 2);
            float4 v = *(const float4*)(x + off);
            half4_t o;
            o.x = (_Float16)v.x; o.y = (_Float16)v.y;
            o.z = (_Float16)v.z; o.w = (_Float16)v.w;
            *(half4_t*)(xh + off) = o;
        }
    } else {
        // crossnet constants. beta_l = sum_{j<l} b_j; c_l = beta_l . w_l.
        __shared__ float redc[4][3];
        const int j = t << 2;
        float4 b0 = *(const float4*)(bs + 0 * H_SZ + j);
        float4 b1 = *(const float4*)(bs + 1 * H_SZ + j);
        float4 b2 = *(const float4*)(bs + 2 * H_SZ + j);
        float4 b3 = *(const float4*)(bs + 3 * H_SZ + j);
        float4 w1 = *(const float4*)(ws + 1 * H_SZ + j);
        float4 w2 = *(const float4*)(ws + 2 * H_SZ + j);
        float4 w3 = *(const float4*)(ws + 3 * H_SZ + j);
        float4 pre1 = b0;
        float4 pre2 = {pre1.x + b1.x, pre1.y + b1.y, pre1.z + b1.z, pre1.w + b1.w};
        float4 pre3 = {pre2.x + b2.x, pre2.y + b2.y, pre2.z + b2.z, pre2.w + b2.w};
        float4 bt   = {pre3.x + b3.x, pre3.y + b3.y, pre3.z + b3.z, pre3.w + b3.w};
        *(float4*)(beta4 + j) = bt;
        float pp[3];
        pp[0] = pre1.x * w1.x + pre1.y * w1.y + pre1.z * w1.z + pre1.w * w1.w;
        pp[1] = pre2.x * w2.x + pre2.y * w2.y + pre2.z * w2.z + pre2.w * w2.w;
        pp[2] = pre3.x * w3.x + pre3.y * w3.y + pre3.z * w3.z + pre3.w * w3.w;
#pragma unroll
        for (int off = 32; off > 0; off >>= 1) {
#pragma unroll
            for (int l = 0; l < 3; ++l) pp[l] += __shfl_down(pp[l], off, 64);
        }
        if ((t & 63) == 0) {
#pragma unroll
            for (int l = 0; l < 3; ++l) redc[t >> 6][l] = pp[l];
        }
        __syncthreads();
        if (t == 0) {
            cvec[0] = 0.0f;
#pragma unroll
            for (int l = 0; l < 3; ++l)
                cvec[l + 1] = redc[0][l] + redc[1][l] + redc[2][l] + redc[3][l];
        }
    }
}

// ---------------------------------------------------------------------------
// Kernel 2: GEMM h = xh @ Wt^T + b_enc. BM=32, BN=64, BK=128. 512 thr =
// 8 waves in 2(m) x 4(n), one 16x16 frag per wave. grid (16,32) = 512
// blocks = 2 blocks/CU. Double-buffered swizzled LDS (48 KB).
// ---------------------------------------------------------------------------
__global__ __launch_bounds__(512, 2) void gemm_kernel(
        const _Float16* __restrict__ xh, const _Float16* __restrict__ Wt,
        const float* __restrict__ b_enc, float* __restrict__ h) {
    // LDS rows of 128 halfs = 16 chunks of 16 B. Physical chunk (r,c) holds
    // logical k-chunk c ^ (r&15) -> fragment reads 2-way (free).
    __shared__ _Float16 As[2][32 * 128];   //  8 KB / buf
    __shared__ _Float16 Bs[2][64 * 128];   // 16 KB / buf
    const int tid  = threadIdx.x;
    const int lane = tid & 63;
    const int w    = tid >> 6;            // 0..7
    const int m0 = blockIdx.y << 5;
    const int n0 = blockIdx.x << 6;
    const int wm = (w >> 2) << 4;         // 0 / 16
    const int wn = (w & 3) << 4;          // 0 / 16 / 32 / 48

    // staging: A 512 slots (1/thread), B 1024 slots (2/thread).
    // slot s -> row r = s>>4, phys chunk s&15, logical chunk (s&15)^(r&15).
    const int ar = tid >> 4;                       // 0..31
    const int ac = ((tid & 15) ^ (ar & 15)) << 3;
    const int br0 = tid >> 4;                      // 0..31
    const int bc0 = ((tid & 15) ^ (br0 & 15)) << 3;
    const int br1 = br0 + 32;                      // 32..63
    const int bc1 = ((tid & 15) ^ (br1 & 15)) << 3;
    const _Float16* aSrc  = xh + (size_t)(m0 + ar) * D_SZ + ac;
    const _Float16* bSrc0 = Wt + (size_t)(n0 + br0) * D_SZ + bc0;
    const _Float16* bSrc1 = Wt + (size_t)(n0 + br1) * D_SZ + bc1;

    // fragment geometry (16x16x32): A[m=lane&15][k=q*8+j], B symmetric.
    const int ra = wm + (lane & 15);
    const int rb = wn + (lane & 15);
    const int q  = lane >> 4;

    floatx4_t acc = {0.0f, 0.0f, 0.0f, 0.0f};

    async_copy16(aSrc, &As[0][tid << 3]);
    async_copy16(bSrc0, &Bs[0][tid << 3]);
    async_copy16(bSrc1, &Bs[0][(tid + 512) << 3]);

    for (int it = 0; it < 8; ++it) {
        __syncthreads();   // drains stage(it); all waves done reading buf[(it+1)&1]
        if (it + 1 < 8) {
            int k0 = (it + 1) << 7;
            int buf = (it + 1) & 1;
            async_copy16(aSrc + k0, &As[buf][tid << 3]);
            async_copy16(bSrc0 + k0, &Bs[buf][tid << 3]);
            async_copy16(bSrc1 + k0, &Bs[buf][(tid + 512) << 3]);
        }
        const _Float16* Ab = As[it & 1];
        const _Float16* Bb = Bs[it & 1];
#pragma unroll
        for (int kk = 0; kk < 4; ++kk) {
            int l = (kk << 2) + q;
            half8_t af = *(const half8_t*)(Ab + ra * 128 + ((l ^ (ra & 15)) << 3));
            half8_t bf = *(const half8_t*)(Bb + rb * 128 + ((l ^ (rb & 15)) << 3));
            acc = __builtin_amdgcn_mfma_f32_16x16x32_f16(af, bf, acc, 0, 0, 0);
        }
    }

    // C/D: col = lane&15, row = (lane>>4)*4 + reg. b_enc folded in here.
    const int col  = n0 + wn + (lane & 15);
    const int row0 = m0 + wm + (q << 2);
    const float be = b_enc[col];
#pragma unroll
    for (int r = 0; r < 4; ++r)
        h[(size_t)(row0 + r) * H_SZ + col] = acc[r] + be;
}

// ---------------------------------------------------------------------------
// Kernel 3: CrossNet (affine-collapsed), one block per row, in-place.
//   x0 = h row (b_enc already folded); d_l = x0 . w_l (ONE reduction round);
//   sig: s_l = sig*d_l + c_l, sig += s_l; out = sig*x0 + beta4.
// ---------------------------------------------------------------------------
__global__ __launch_bounds__(256) void crossnet_kernel(
        float* __restrict__ h, const float* __restrict__ ws,
        const float* __restrict__ cvec, const float* __restrict__ beta4) {
    const int row = blockIdx.x;
    const int t = threadIdx.x;
    const int j = t << 2;
    float* hr = h + (size_t)row * H_SZ;

    float4 hv = *(const float4*)(hr + j);
    float x0[4] = {hv.x, hv.y, hv.z, hv.w};

    float p[DEPTH];
#pragma unroll
    for (int l = 0; l < DEPTH; ++l) {
        float4 wv = *(const float4*)(ws + l * H_SZ + j);
        p[l] = x0[0] * wv.x + x0[1] * wv.y + x0[2] * wv.z + x0[3] * wv.w;
    }
#pragma unroll
    for (int off = 32; off > 0; off >>= 1) {
#pragma unroll
        for (int l = 0; l < DEPTH; ++l) p[l] += __shfl_down(p[l], off, 64);
    }
    __shared__ float red[4][DEPTH];
    if ((t & 63) == 0) {
#pragma unroll
        for (int l = 0; l < DEPTH; ++l) red[t >> 6][l] = p[l];
    }
    __syncthreads();

    float sig = 1.0f;
#pragma unroll
    for (int l = 0; l < DEPTH; ++l) {
        float d = red[0][l] + red[1][l] + red[2][l] + red[3][l];
        float s = sig * d + cvec[l];
        sig += s;
    }
    float4 b4 = *(const float4*)(beta4 + j);
    float4 o = {x0[0] * sig + b4.x, x0[1] * sig + b4.y,
                x0[2] * sig + b4.z, x0[3] * sig + b4.w};
    *(float4*)(hr + j) = o;
}

extern "C" void kernel_launch(void* const* d_in, const int* in_sizes, int n_in,
                              void* d_out, int out_size, void* d_ws, size_t ws_size,
                              hipStream_t stream) {
    const float* x     = (const float*)d_in[0];
    const float* W_enc = (const float*)d_in[1];
    const float* b_enc = (const float*)d_in[2];
    const float* ws    = (const float*)d_in[3];
    const float* bs    = (const float*)d_in[4];
    float* out = (float*)d_out;

    _Float16* xh = (_Float16*)d_ws;                 // 2 MB
    _Float16* Wt = xh + (size_t)B_SZ * D_SZ;        // 2 MB
    float* aux   = (float*)((char*)d_ws + 4u * 1024u * 1024u);
    float* cvec  = aux;                             // 4 floats
    float* beta4 = aux + 4;                         // 1024 floats (16B-aligned)

    prep_kernel<<<513, 256, 0, stream>>>(x, W_enc, ws, bs, xh, Wt, cvec, beta4);
    dim3 grid(H_SZ / 64, B_SZ / 32);                // (n-tiles, m-tiles)
    gemm_kernel<<<grid, 512, 0, stream>>>(xh, Wt, b_enc, out);
    crossnet_kernel<<<B_SZ, 256, 0, stream>>>(out, ws, cvec, beta4);
}